// Round 15
// baseline (305.370 us; speedup 1.0000x reference)
//
#include <hip/hip_runtime.h>
#include <cstddef>
#include <cstdint>

#define NN 8192
#define DD 128
#define KP 128          // panel K-dim: cross = 2 * YS @ X^T  (S symmetric)
#define BM 128
#define BN 128
#define BK 32
#define NREG 12         // 3 passes (Ah.Bh, Ah.Bl, Al.Bh) x 4 k-steps
#define JSPLIT 8
#define JRANGE (NN / JSPLIT)    // 1024
#define NJT (JRANGE / BN)       // 8
#define THRESH 1e-32f   // K below this is stored as 0 / tile-skipped

typedef __attribute__((ext_vector_type(8))) short bf16x8;
typedef __attribute__((ext_vector_type(4))) float f32x4;
typedef unsigned short u16;
typedef unsigned int   u32;

__device__ __forceinline__ u16 f2bf(float x) {
    u32 u = __float_as_uint(x);
    u32 r = (u + 0x7fffu + ((u >> 16) & 1u)) >> 16;   // round-to-nearest-even
    return (u16)r;
}
__device__ __forceinline__ float bf2f(u16 h) {
    return __uint_as_float(((u32)h) << 16);
}

// async global->LDS, 16B per lane; LDS dest is wave-uniform base (+lane*16 by HW)
#define GLDS16(gp, lp) __builtin_amdgcn_global_load_lds( \
    (const __attribute__((address_space(1))) void*)(gp), \
    (__attribute__((address_space(3))) void*)(lp), 16, 0, 0)

#define VMCNT(n) asm volatile("s_waitcnt vmcnt(" #n ")" ::: "memory")
#define BARRIER() do { __builtin_amdgcn_s_barrier(); asm volatile("" ::: "memory"); } while (0)

// 16B-chunk swizzle within a 64B staging row: free 2-way bank pattern on read
#define SWZ_CHUNK(row, c) ((c) ^ (((row) >> 1) & 3))

// ---------------------------------------------------------------------------
// k1: XS=X@S, YS=Y@S, qX, qY; bf16 hi/lo panels Ah/Al=YS, Bh/Bl=X
// (row-major [8192][128]), XST = bf16 XS^T [128][8192], YSrm fp32 [8192][128].
// ---------------------------------------------------------------------------
__global__ __launch_bounds__(256) void k1_precompute(
    const float* __restrict__ X, const float* __restrict__ Y,
    const float* __restrict__ S,
    u16* __restrict__ Ah, u16* __restrict__ Al,
    u16* __restrict__ Bh, u16* __restrict__ Bl,
    u16* __restrict__ XST, float* __restrict__ YSrm,
    float* __restrict__ qX, float* __restrict__ qY)
{
    __shared__ float Xs[16][128];
    __shared__ float Ys[16][128];
    __shared__ float XSb[16][129];
    __shared__ float YSb[16][129];
    const int t  = threadIdx.x;
    const int i0 = blockIdx.x * 16;

    #pragma unroll
    for (int p = 0; p < 2; ++p) {
        int f4 = t + p * 256;          // 0..511
        int r  = f4 >> 5;
        int c  = (f4 & 31) * 4;
        *reinterpret_cast<float4*>(&Xs[r][c]) =
            *reinterpret_cast<const float4*>(X + (size_t)(i0 + r) * DD + c);
        *reinterpret_cast<float4*>(&Ys[r][c]) =
            *reinterpret_cast<const float4*>(Y + (size_t)(i0 + r) * DD + c);
    }
    __syncthreads();

    const int d    = t & 127;
    const int half = t >> 7;
    float xsa[8], ysa[8];
    #pragma unroll
    for (int r = 0; r < 8; ++r) { xsa[r] = 0.f; ysa[r] = 0.f; }
    for (int k = 0; k < DD; ++k) {
        float sv = S[k * DD + d];
        #pragma unroll
        for (int r = 0; r < 8; ++r) {
            xsa[r] = fmaf(Xs[half*8 + r][k], sv, xsa[r]);
            ysa[r] = fmaf(Ys[half*8 + r][k], sv, ysa[r]);
        }
    }
    #pragma unroll
    for (int r = 0; r < 8; ++r) {
        XSb[half*8 + r][d] = xsa[r];
        YSb[half*8 + r][d] = ysa[r];
    }
    __syncthreads();

    if (t < 16) {
        float s = 0.f;
        for (int k = 0; k < DD; ++k) s += Xs[t][k] * XSb[t][k];
        qX[i0 + t] = s;
    } else if (t < 32) {
        int r = t - 16;
        float s = 0.f;
        for (int k = 0; k < DD; ++k) s += Ys[r][k] * YSb[r][k];
        qY[i0 + r] = s;
    }

    // hi/lo split panels (YS -> A, X -> B), 2 cols per u32 store
    #pragma unroll
    for (int p = 0; p < 4; ++p) {
        int e  = t + p * 256;          // 0..1023
        int r  = e >> 6;               // 0..15
        int c2 = (e & 63) * 2;         // 0,2,..,126
        float a0 = YSb[r][c2], a1 = YSb[r][c2 + 1];
        float b0 = Xs[r][c2],  b1 = Xs[r][c2 + 1];
        u16 ah0 = f2bf(a0), ah1 = f2bf(a1);
        u16 al0 = f2bf(a0 - bf2f(ah0)), al1 = f2bf(a1 - bf2f(ah1));
        u16 bh0 = f2bf(b0), bh1 = f2bf(b1);
        u16 bl0 = f2bf(b0 - bf2f(bh0)), bl1 = f2bf(b1 - bf2f(bh1));
        size_t off = (size_t)(i0 + r) * KP + c2;
        *reinterpret_cast<u32*>(Ah + off) = (u32)ah0 | ((u32)ah1 << 16);
        *reinterpret_cast<u32*>(Al + off) = (u32)al0 | ((u32)al1 << 16);
        *reinterpret_cast<u32*>(Bh + off) = (u32)bh0 | ((u32)bh1 << 16);
        *reinterpret_cast<u32*>(Bl + off) = (u32)bl0 | ((u32)bl1 << 16);
    }
    // XS^T bf16
    #pragma unroll
    for (int p = 0; p < 8; ++p) {
        int e  = t + p * 256;          // 0..2047
        int dd = e >> 4;               // 0..127
        int r  = e & 15;
        XST[(size_t)dd * NN + i0 + r] = f2bf(XSb[r][dd]);
    }
    // YS fp32 row-major
    #pragma unroll
    for (int p = 0; p < 8; ++p) {
        int e  = t + p * 256;
        int r  = e >> 7;
        int dd = e & 127;
        YSrm[(size_t)(i0 + r) * DD + dd] = YSb[r][dd];
    }
}

// ---------------------------------------------------------------------------
// k2 (512 threads, 8 waves, exactly 80 KB LDS -> 2 blocks/CU), fused
// GEMM + phase 2. acc = YSh.Xh^T + YSh.Xl^T + YSl.Xh^T (K=128, 12 regions);
// quad uses 2*acc.
// Output strategy (cross-round evidence): per-block fused zero_tile writes
// FULL 512B rows (complete L2 lines -> no HBM RMW; R9 FETCH=32MB), sparse
// epilogue stores only where K > THRESH (~1 MB). Dense 64B-sliced epilogue
// stores at 2 blocks/CU caused partial-line RMW (R14: FETCH 330MB,
// WRITE 590MB). Dedicated burst fills amplify ~4x (R8/R11: 1.09GB, 160us).
// Phase-2 skip via manual wave flags in b0 + double barrier; __any is
// evaluated with ALL lanes active (inside if(lane==0) it reduces over lane
// 0 only — the R10/R13 bug). Manual flags avoid __syncthreads_count's
// +512B hidden LDS (R9/R12: LDS 82432 -> 1 block/CU, exposed zero-drain).
// LDS map: b0 [0,16K) b1 [16K,32K) b2 [32K,48K) XT2 [48K,80K); A2 = b0+b1.
// ---------------------------------------------------------------------------
__device__ __forceinline__ void get_ops(
    const u16* Ah, const u16* Al, const u16* Bh, const u16* Bl,
    int kg, const u16** Ap, const u16** Bp, int* kc)
{
    const int pass = kg >> 2;
    *kc = (kg & 3) * BK;
    *Ap = (pass == 2) ? Al : Ah;
    *Bp = (pass == 1) ? Bl : Bh;
}

__device__ __forceinline__ void stage_ab8(
    const u16* __restrict__ Ap, const u16* __restrict__ Bp,
    int ib, int jb, int kc, unsigned char* lds, int wid, int lane)
{
    const int rr = wid * 16 + (lane >> 2);         // row 0..127 (wave-chunk wid)
    const int cc = SWZ_CHUNK(rr, lane & 3) * 8;    // swizzled u16 col
    GLDS16(Ap + (size_t)(ib + rr) * KP + kc + cc, lds + wid * 1024);
    GLDS16(Bp + (size_t)(jb + rr) * KP + kc + cc, lds + 8192 + wid * 1024);
}

// zero one 128x128 K-tile (64 KB): 8 float4 stores/thread, full 512B rows
// (complete L2 lines -> no partial-line RMW). Issued BEFORE staging loads
// so the existing FIFO vmcnt waits drain them with no extra fence.
__device__ __forceinline__ void zero_tile(
    float* __restrict__ Kout, int ib, int jb, int t)
{
    #pragma unroll
    for (int s = 0; s < 8; ++s) {
        const int idx = s * 512 + t;          // 0..4095 float4s
        const int row = idx >> 5;             // 0..127 (32 float4 per row)
        const int col = (idx & 31) * 4;
        *reinterpret_cast<float4*>(Kout + (size_t)(ib + row) * NN + jb + col) =
            make_float4(0.f, 0.f, 0.f, 0.f);
    }
}

__global__ __launch_bounds__(512, 4) void k2_main(
    const u16* __restrict__ Ah, const u16* __restrict__ Al,
    const u16* __restrict__ Bh, const u16* __restrict__ Bl,
    const u16* __restrict__ XST,
    const float* __restrict__ qX, const float* __restrict__ qY,
    float* __restrict__ Kout, float* __restrict__ daccOut,
    float* __restrict__ rowsum, int usePart)
{
    __shared__ unsigned char smem[81920];

    const int t    = threadIdx.x;
    const int wid  = t >> 6;                // 0..7
    const int lane = t & 63;
    const int lq   = lane >> 4;             // quarter 0..3
    const int lc   = lane & 15;
    const int wir  = wid >> 1;              // i 32-quarter (0..3)
    const int wjc  = wid & 1;               // j 64-half (0..1)

    // per-XCD rectangle: XCD x owns strips [(x&3)*16,+16) x jsp [(x>>2)*4,+4)
    const int bid   = blockIdx.x;
    const int xcd   = bid & 7;
    const int rb    = bid >> 3;             // 0..63
    const int strip = (xcd & 3) * 16 + (rb & 15);
    const int jsp   = (xcd >> 2) * 4 + (rb >> 4);
    const int ib    = strip * BM;
    const int jbase = jsp * JRANGE;

    // per-lane row constants: i = ib + wir*32 + ni*16 + lc  (0.5*qY folded)
    float qYh[2];
    #pragma unroll
    for (int ni = 0; ni < 2; ++ni)
        qYh[ni] = 0.5f * qY[ib + wir*32 + ni*16 + lc];

    f32x4 dacc[2][4];
    #pragma unroll
    for (int a = 0; a < 2; ++a)
        #pragma unroll
        for (int b = 0; b < 4; ++b)
            dacc[a][b] = (f32x4){0.f, 0.f, 0.f, 0.f};
    float rs[2] = {0.f, 0.f};

    // zero this block's first K-tile; drained by the prologue VMCNT(6)
    zero_tile(Kout, ib, jbase, t);

    for (int jt = 0; jt < NJT; ++jt) {
        const int jb = jbase + jt * BN;

        // zero NEXT tile's region (issued before staging loads: FIFO vmcnt
        // drains these during this iteration's counted waits, a full
        // iteration before that tile's sparse epilogue stores)
        if (jt + 1 < NJT)
            zero_tile(Kout, ib, jb + BN, t);

        // ---- prologue: stage kg=0 -> b0, kg=1 -> b1, then XT2 prefetch ----
        {
            const u16 *Ap, *Bp; int kc;
            get_ops(Ah, Al, Bh, Bl, 0, &Ap, &Bp, &kc);
            stage_ab8(Ap, Bp, ib, jb, kc, smem, wid, lane);
            get_ops(Ah, Al, Bh, Bl, 1, &Ap, &Bp, &kc);
            stage_ab8(Ap, Bp, ib, jb, kc, smem + 16384, wid, lane);
        }
        #pragma unroll
        for (int c = 0; c < 4; ++c) {
            int chunk = wid * 4 + c;              // 0..31
            int dd = chunk * 4 + lq;              // 0..127
            int ch = lc ^ (dd & 7);               // pre-swizzled 16B granule
            GLDS16(XST + (size_t)dd * NN + jb + ch*8,
                   smem + 49152 + (size_t)chunk * 1024);
        }
        VMCNT(6);           // all older VMEM (zero stores, prior sparse
                            // stores, s0) done; s1 + XT2 still in flight
        BARRIER();

        f32x4 acc[4][2];    // [mj][ni]
        #pragma unroll
        for (int a = 0; a < 4; ++a)
            #pragma unroll
            for (int b = 0; b < 2; ++b)
                acc[a][b] = (f32x4){0.f, 0.f, 0.f, 0.f};

        // ---- main pipeline: 12 regions, one barrier each, counted vmcnt ----
        #pragma unroll 3
        for (int kg = 0; kg < NREG; ++kg) {
            if (kg <= NREG - 3) {
                const u16 *Ap, *Bp; int kc;
                get_ops(Ah, Al, Bh, Bl, kg + 2, &Ap, &Bp, &kc);
                stage_ab8(Ap, Bp, ib, jb, kc, smem + ((kg + 2) % 3) * 16384, wid, lane);
            }
            const u16* BufA = (const u16*)(smem + (kg % 3) * 16384);  // YS rows
            const u16* BufB = BufA + 4096;                             // X rows

            bf16x8 xf[4], yf[2];
            #pragma unroll
            for (int mj = 0; mj < 4; ++mj) {
                const int br = wjc*64 + mj*16 + lc;
                xf[mj] = *reinterpret_cast<const bf16x8*>(
                    BufB + br * BK + SWZ_CHUNK(br, lq) * 8);
            }
            #pragma unroll
            for (int ni = 0; ni < 2; ++ni) {
                const int ar = wir*32 + ni*16 + lc;
                yf[ni] = *reinterpret_cast<const bf16x8*>(
                    BufA + ar * BK + SWZ_CHUNK(ar, lq) * 8);
            }
            __builtin_amdgcn_s_setprio(1);
            #pragma unroll
            for (int mj = 0; mj < 4; ++mj)
                #pragma unroll
                for (int ni = 0; ni < 2; ++ni)
                    acc[mj][ni] = __builtin_amdgcn_mfma_f32_16x16x32_bf16(
                        xf[mj], yf[ni], acc[mj][ni], 0, 0, 0);
            __builtin_amdgcn_s_setprio(0);

            if (kg == 0)            VMCNT(6);   // drain s1 (XT2+s2 in flight)
            else if (kg <= NREG-3)  VMCNT(2);   // drain s_{kg+1}, keep s_{kg+2}
            else if (kg == NREG-2)  VMCNT(0);   // drain s_{NREG-1}
            if (kg < NREG-1) BARRIER();
            // last region: no barrier — epilogue touches no LDS until the
            // flag write into b0 (b0's last reader finished at region
            // NREG-3's barrier; region NREG-1 reads only b2).
        }

        // ---- epilogue: K = exp(acc - 0.5qY - 0.5qX); SPARSE float4 Kout
        //      (tile pre-zeroed above); kq kept in acc for phase 2 ----
        float tmax = 0.f;
        #pragma unroll
        for (int mj = 0; mj < 4; ++mj) {
            const int jl = wjc*64 + mj*16 + lq*4;      // local j of reg 0
            float4 qXv = *reinterpret_cast<const float4*>(qX + jb + jl);
            qXv.x *= 0.5f; qXv.y *= 0.5f; qXv.z *= 0.5f; qXv.w *= 0.5f;
            #pragma unroll
            for (int ni = 0; ni < 2; ++ni) {
                const int il = wir*32 + ni*16 + lc;    // local i
                float kq0 = __expf(acc[mj][ni][0] - qYh[ni] - qXv.x);
                float kq1 = __expf(acc[mj][ni][1] - qYh[ni] - qXv.y);
                float kq2 = __expf(acc[mj][ni][2] - qYh[ni] - qXv.z);
                float kq3 = __expf(acc[mj][ni][3] - qYh[ni] - qXv.w);
                rs[ni] += kq0 + kq1 + kq2 + kq3;
                float m4 = fmaxf(fmaxf(kq0, kq1), fmaxf(kq2, kq3));
                tmax = fmaxf(tmax, m4);
                if (m4 > THRESH)
                    *reinterpret_cast<float4*>(
                        Kout + (size_t)(ib + il) * NN + jb + jl) =
                        make_float4(kq0, kq1, kq2, kq3);
                acc[mj][ni][0] = kq0; acc[mj][ni][1] = kq1;
                acc[mj][ni][2] = kq2; acc[mj][ni][3] = kq3;
            }
        }

        // ---- tile-wide nonzero test: wave flags in b0, double barrier.
        //      __any evaluated with ALL lanes active; all waves read flags
        //      between the same two barriers -> block-uniform nz; b0 is not
        //      reused until every wave passes barrier #2. ----
        {
            const int wflag = __any(tmax > THRESH) ? 1 : 0;   // full-wave reduce
            volatile int* flags = (volatile int*)smem;
            if (lane == 0)
                flags[wid] = wflag;
            __syncthreads();               // flag writes visible
            int nz = 0;
            #pragma unroll
            for (int w = 0; w < 8; ++w) nz |= flags[w];
            __syncthreads();               // all flag READS done before b0 reuse

            if (nz != 0) {
                // bf16 K into A2 [i][j] row-major, 16B-granule XOR swizzle
                #pragma unroll
                for (int mj = 0; mj < 4; ++mj) {
                    const int jl = wjc*64 + mj*16 + lq*4;
                    #pragma unroll
                    for (int ni = 0; ni < 2; ++ni) {
                        const int il = wir*32 + ni*16 + lc;
                        u32 p0 = (u32)f2bf(acc[mj][ni][0]) | ((u32)f2bf(acc[mj][ni][1]) << 16);
                        u32 p1 = (u32)f2bf(acc[mj][ni][2]) | ((u32)f2bf(acc[mj][ni][3]) << 16);
                        const int by = il*256 + ((jl*2) ^ ((il & 7) << 4));
                        *reinterpret_cast<uint2*>(smem + by) = make_uint2(p0, p1);
                    }
                }
                __syncthreads();   // A2 visible to all

                // ---- phase 2: dacc[i][d] += K_tile[i][j] * XS[j][d] ----
                #pragma unroll
                for (int kb = 0; kb < 4; ++kb) {
                    bf16x8 pa[2], pb[4];
                    #pragma unroll
                    for (int mi = 0; mi < 2; ++mi) {
                        const int il = wir*32 + mi*16 + lc;
                        const int gr = (kb*4 + lq) ^ (il & 7);
                        pa[mi] = *reinterpret_cast<const bf16x8*>(smem + il*256 + gr*16);
                    }
                    #pragma unroll
                    for (int di = 0; di < 4; ++di) {
                        const int dl = wjc*64 + di*16 + lc;
                        const int gr = (kb*4 + lq) ^ (dl & 7);
                        pb[di] = *reinterpret_cast<const bf16x8*>(smem + 49152 + dl*256 + gr*16);
                    }
                    #pragma unroll
                    for (int mi = 0; mi < 2; ++mi)
                        #pragma unroll
                        for (int di = 0; di < 4; ++di)
                            dacc[mi][di] = __builtin_amdgcn_mfma_f32_16x16x32_bf16(
                                pa[mi], pb[di], dacc[mi][di], 0, 0, 0);
                }
                __syncthreads();   // phase-2 reads done before next jt restages
            }
            // nz==0: barrier #2 already fenced all flag reads and epilogue;
            // A2 was never written, so next-tile staging into b0 is safe.
        }
    }

    // ---- write out dacc: plain stores to per-jsp partial, or atomic ----
    if (usePart) {
        float* P = daccOut + (size_t)jsp * NN * DD;
        #pragma unroll
        for (int mi = 0; mi < 2; ++mi) {
            #pragma unroll
            for (int di = 0; di < 4; ++di) {
                const int col = wjc*64 + di*16 + lc;
                #pragma unroll
                for (int rr = 0; rr < 4; ++rr) {
                    const int row = ib + wir*32 + mi*16 + lq*4 + rr;
                    P[(size_t)row * DD + col] = dacc[mi][di][rr];
                }
            }
        }
    } else {
        #pragma unroll
        for (int mi = 0; mi < 2; ++mi) {
            #pragma unroll
            for (int di = 0; di < 4; ++di) {
                const int col = wjc*64 + di*16 + lc;
                #pragma unroll
                for (int rr = 0; rr < 4; ++rr) {
                    const int row = ib + wir*32 + mi*16 + lq*4 + rr;
                    atomicAdd(&daccOut[(size_t)row * DD + col], dacc[mi][di][rr]);
                }
            }
        }
    }
    #pragma unroll
    for (int ni = 0; ni < 2; ++ni) {
        float v = rs[ni];
        v += __shfl_xor(v, 16);
        v += __shfl_xor(v, 32);
        if (lq == 0)
            atomicAdd(&rowsum[ib + wir*32 + ni*16 + lc], v);
    }
}

// dK = 2*(rowsum[i]*YS[i][d] - acc[i][d]); acc = sum of partials (usePart)
// or lives in the dK buffer itself (atomic fallback, in-place).
__global__ __launch_bounds__(256) void k3_finalize(
    const float* __restrict__ rowsum, const float* __restrict__ YSrm,
    float* __restrict__ dK, const float* __restrict__ parts, int usePart)
{
    int idx = blockIdx.x * 256 + threadIdx.x;
    int i = idx >> 7;
    float a;
    if (usePart) {
        a = 0.f;
        #pragma unroll
        for (int s = 0; s < JSPLIT; ++s)
            a += parts[(size_t)s * NN * DD + idx];
    } else {
        a = dK[idx];
    }
    dK[idx] = 2.0f * (rowsum[i] * YSrm[idx] - a);
}

extern "C" void kernel_launch(void* const* d_in, const int* in_sizes, int n_in,
                              void* d_out, int out_size, void* d_ws, size_t ws_size,
                              hipStream_t stream)
{
    const float* X = (const float*)d_in[0];
    const float* Y = (const float*)d_in[1];
    const float* S = (const float*)d_in[2];
    float* Kout = (float*)d_out;
    float* dK   = Kout + (size_t)NN * NN;

    u16* Ah  = (u16*)d_ws;
    u16* Al  = Ah + (size_t)NN * KP;
    u16* Bh  = Al + (size_t)NN * KP;
    u16* Bl  = Bh + (size_t)NN * KP;
    u16* XST = Bl + (size_t)NN * KP;
    float* YSrm = (float*)(XST + (size_t)DD * NN);
    float* qX   = YSrm + (size_t)NN * DD;
    float* qY   = qX + NN;
    float* rsum = qY + NN;
    float* parts = rsum + NN;

    const size_t baseBytes = (size_t)((char*)(parts) - (char*)d_ws);
    const size_t needBytes = baseBytes + (size_t)JSPLIT * NN * DD * sizeof(float);
    const int usePart = (ws_size >= needBytes) ? 1 : 0;

    hipMemsetAsync(rsum, 0, (size_t)NN * sizeof(float), stream);
    if (!usePart)
        hipMemsetAsync(dK, 0, (size_t)NN * DD * sizeof(float), stream);

    float* daccOut = usePart ? parts : dK;

    k1_precompute<<<NN / 16, 256, 0, stream>>>(X, Y, S, Ah, Al, Bh, Bl, XST, YSrm, qX, qY);
    k2_main<<<64 * JSPLIT, 512, 0, stream>>>(Ah, Al, Bh, Bl, XST, qX, qY,
                                             Kout, daccOut, rsum, usePart);
    k3_finalize<<<(NN * DD) / 256, 256, 0, stream>>>(rsum, YSrm, dK, parts, usePart);
}

// Round 16
// 203.339 us; speedup vs baseline: 1.5018x; 1.5018x over previous
//
#include <hip/hip_runtime.h>
#include <cstddef>
#include <cstdint>

#define NN 8192
#define DD 128
#define KP 128          // panel K-dim: cross = 2 * YS @ X^T  (S symmetric)
#define BM 128
#define BN 128
#define BK 32
#define NREG 12         // 3 passes (Ah.Bh, Ah.Bl, Al.Bh) x 4 k-steps
#define JSPLIT 8
#define JRANGE (NN / JSPLIT)    // 1024
#define NJT (JRANGE / BN)       // 8
#define THRESH 1e-32f   // K below this is stored as 0 / tile-skipped

typedef __attribute__((ext_vector_type(8))) short bf16x8;
typedef __attribute__((ext_vector_type(4))) float f32x4;
typedef unsigned short u16;
typedef unsigned int   u32;

__device__ __forceinline__ u16 f2bf(float x) {
    u32 u = __float_as_uint(x);
    u32 r = (u + 0x7fffu + ((u >> 16) & 1u)) >> 16;   // round-to-nearest-even
    return (u16)r;
}
__device__ __forceinline__ float bf2f(u16 h) {
    return __uint_as_float(((u32)h) << 16);
}

// async global->LDS, 16B per lane; LDS dest is wave-uniform base (+lane*16 by HW)
#define GLDS16(gp, lp) __builtin_amdgcn_global_load_lds( \
    (const __attribute__((address_space(1))) void*)(gp), \
    (__attribute__((address_space(3))) void*)(lp), 16, 0, 0)

#define VMCNT(n) asm volatile("s_waitcnt vmcnt(" #n ")" ::: "memory")
#define BARRIER() do { __builtin_amdgcn_s_barrier(); asm volatile("" ::: "memory"); } while (0)

// 16B-chunk swizzle within a 64B staging row: free 2-way bank pattern on read
#define SWZ_CHUNK(row, c) ((c) ^ (((row) >> 1) & 3))

// ---------------------------------------------------------------------------
// k1: XS=X@S, YS=Y@S, qX, qY; bf16 hi/lo panels Ah/Al=YS, Bh/Bl=X
// (row-major [8192][128]), XST = bf16 XS^T [128][8192], YSrm fp32 [8192][128].
// ---------------------------------------------------------------------------
__global__ __launch_bounds__(256) void k1_precompute(
    const float* __restrict__ X, const float* __restrict__ Y,
    const float* __restrict__ S,
    u16* __restrict__ Ah, u16* __restrict__ Al,
    u16* __restrict__ Bh, u16* __restrict__ Bl,
    u16* __restrict__ XST, float* __restrict__ YSrm,
    float* __restrict__ qX, float* __restrict__ qY)
{
    __shared__ float Xs[16][128];
    __shared__ float Ys[16][128];
    __shared__ float XSb[16][129];
    __shared__ float YSb[16][129];
    const int t  = threadIdx.x;
    const int i0 = blockIdx.x * 16;

    #pragma unroll
    for (int p = 0; p < 2; ++p) {
        int f4 = t + p * 256;          // 0..511
        int r  = f4 >> 5;
        int c  = (f4 & 31) * 4;
        *reinterpret_cast<float4*>(&Xs[r][c]) =
            *reinterpret_cast<const float4*>(X + (size_t)(i0 + r) * DD + c);
        *reinterpret_cast<float4*>(&Ys[r][c]) =
            *reinterpret_cast<const float4*>(Y + (size_t)(i0 + r) * DD + c);
    }
    __syncthreads();

    const int d    = t & 127;
    const int half = t >> 7;
    float xsa[8], ysa[8];
    #pragma unroll
    for (int r = 0; r < 8; ++r) { xsa[r] = 0.f; ysa[r] = 0.f; }
    for (int k = 0; k < DD; ++k) {
        float sv = S[k * DD + d];
        #pragma unroll
        for (int r = 0; r < 8; ++r) {
            xsa[r] = fmaf(Xs[half*8 + r][k], sv, xsa[r]);
            ysa[r] = fmaf(Ys[half*8 + r][k], sv, ysa[r]);
        }
    }
    #pragma unroll
    for (int r = 0; r < 8; ++r) {
        XSb[half*8 + r][d] = xsa[r];
        YSb[half*8 + r][d] = ysa[r];
    }
    __syncthreads();

    if (t < 16) {
        float s = 0.f;
        for (int k = 0; k < DD; ++k) s += Xs[t][k] * XSb[t][k];
        qX[i0 + t] = s;
    } else if (t < 32) {
        int r = t - 16;
        float s = 0.f;
        for (int k = 0; k < DD; ++k) s += Ys[r][k] * YSb[r][k];
        qY[i0 + r] = s;
    }

    // hi/lo split panels (YS -> A, X -> B), 2 cols per u32 store
    #pragma unroll
    for (int p = 0; p < 4; ++p) {
        int e  = t + p * 256;          // 0..1023
        int r  = e >> 6;               // 0..15
        int c2 = (e & 63) * 2;         // 0,2,..,126
        float a0 = YSb[r][c2], a1 = YSb[r][c2 + 1];
        float b0 = Xs[r][c2],  b1 = Xs[r][c2 + 1];
        u16 ah0 = f2bf(a0), ah1 = f2bf(a1);
        u16 al0 = f2bf(a0 - bf2f(ah0)), al1 = f2bf(a1 - bf2f(ah1));
        u16 bh0 = f2bf(b0), bh1 = f2bf(b1);
        u16 bl0 = f2bf(b0 - bf2f(bh0)), bl1 = f2bf(b1 - bf2f(bh1));
        size_t off = (size_t)(i0 + r) * KP + c2;
        *reinterpret_cast<u32*>(Ah + off) = (u32)ah0 | ((u32)ah1 << 16);
        *reinterpret_cast<u32*>(Al + off) = (u32)al0 | ((u32)al1 << 16);
        *reinterpret_cast<u32*>(Bh + off) = (u32)bh0 | ((u32)bh1 << 16);
        *reinterpret_cast<u32*>(Bl + off) = (u32)bl0 | ((u32)bl1 << 16);
    }
    // XS^T bf16
    #pragma unroll
    for (int p = 0; p < 8; ++p) {
        int e  = t + p * 256;          // 0..2047
        int dd = e >> 4;               // 0..127
        int r  = e & 15;
        XST[(size_t)dd * NN + i0 + r] = f2bf(XSb[r][dd]);
    }
    // YS fp32 row-major
    #pragma unroll
    for (int p = 0; p < 8; ++p) {
        int e  = t + p * 256;
        int r  = e >> 7;
        int dd = e & 127;
        YSrm[(size_t)(i0 + r) * DD + dd] = YSb[r][dd];
    }
}

// ---------------------------------------------------------------------------
// k2 (512 threads, 8 waves, 96 KB LDS -> 1 block/CU BY DESIGN):
// cross-round 2x2 (R9/R12/R14/R15): at 2 blocks/CU ANY 268MB store stream
// amplifies (~Kout-sized FETCH + 2x WRITE: L2 write-combine window
// overflow); at 1 block/CU no amplification. So pin 1 block/CU and spend
// the freed LDS on pipeline depth: 4 staging buffers, 3-ahead prefetch
// (each stage gets 2-3 regions of latency slack vs R9's 1).
// acc = YSh.Xh^T + YSh.Xl^T + YSl.Xh^T (K=128, 12 regions); quad = 2*acc.
// Output: fused zero_tile (full 512B rows) + sparse epilogue stores
// (R9-proven); phase-2 skip via __syncthreads_count (R9-proven; its +512B
// LDS is irrelevant at 1 block/CU).
// LDS map: b0..b3 [0,64K) (16K each), XT2 [64K,96K); A2 aliases b0+b1.
// vmcnt ledger ("N youngest kept" — robust to older zero/sparse stores):
// prologue VMCNT(8) [keep s1,s2,XT2]; kg=0,1: (8); kg=2..8: (4)
// [keep s_{kg+2},s_{kg+3}]; kg=9: (2); kg=10: (0); kg=11: none.
// ---------------------------------------------------------------------------
__device__ __forceinline__ void get_ops(
    const u16* Ah, const u16* Al, const u16* Bh, const u16* Bl,
    int kg, const u16** Ap, const u16** Bp, int* kc)
{
    const int pass = kg >> 2;
    *kc = (kg & 3) * BK;
    *Ap = (pass == 2) ? Al : Ah;
    *Bp = (pass == 1) ? Bl : Bh;
}

__device__ __forceinline__ void stage_ab8(
    const u16* __restrict__ Ap, const u16* __restrict__ Bp,
    int ib, int jb, int kc, unsigned char* lds, int wid, int lane)
{
    const int rr = wid * 16 + (lane >> 2);         // row 0..127 (wave-chunk wid)
    const int cc = SWZ_CHUNK(rr, lane & 3) * 8;    // swizzled u16 col
    GLDS16(Ap + (size_t)(ib + rr) * KP + kc + cc, lds + wid * 1024);
    GLDS16(Bp + (size_t)(jb + rr) * KP + kc + cc, lds + 8192 + wid * 1024);
}

// zero one 128x128 K-tile (64 KB): 8 float4 stores/thread, full 512B rows
// (complete L2 lines). Issued BEFORE staging loads; drained by the
// prologue's counted vmcnt with no extra fence.
__device__ __forceinline__ void zero_tile(
    float* __restrict__ Kout, int ib, int jb, int t)
{
    #pragma unroll
    for (int s = 0; s < 8; ++s) {
        const int idx = s * 512 + t;          // 0..4095 float4s
        const int row = idx >> 5;             // 0..127 (32 float4 per row)
        const int col = (idx & 31) * 4;
        *reinterpret_cast<float4*>(Kout + (size_t)(ib + row) * NN + jb + col) =
            make_float4(0.f, 0.f, 0.f, 0.f);
    }
}

__global__ __launch_bounds__(512, 2) void k2_main(
    const u16* __restrict__ Ah, const u16* __restrict__ Al,
    const u16* __restrict__ Bh, const u16* __restrict__ Bl,
    const u16* __restrict__ XST,
    const float* __restrict__ qX, const float* __restrict__ qY,
    float* __restrict__ Kout, float* __restrict__ daccOut,
    float* __restrict__ rowsum, int usePart)
{
    __shared__ unsigned char smem[98304];   // b0..b3 + XT2

    const int t    = threadIdx.x;
    const int wid  = t >> 6;                // 0..7
    const int lane = t & 63;
    const int lq   = lane >> 4;             // quarter 0..3
    const int lc   = lane & 15;
    const int wir  = wid >> 1;              // i 32-quarter (0..3)
    const int wjc  = wid & 1;               // j 64-half (0..1)

    // per-XCD rectangle: XCD x owns strips [(x&3)*16,+16) x jsp [(x>>2)*4,+4)
    const int bid   = blockIdx.x;
    const int xcd   = bid & 7;
    const int rb    = bid >> 3;             // 0..63
    const int strip = (xcd & 3) * 16 + (rb & 15);
    const int jsp   = (xcd >> 2) * 4 + (rb >> 4);
    const int ib    = strip * BM;
    const int jbase = jsp * JRANGE;

    // per-lane row constants: i = ib + wir*32 + ni*16 + lc  (0.5*qY folded)
    float qYh[2];
    #pragma unroll
    for (int ni = 0; ni < 2; ++ni)
        qYh[ni] = 0.5f * qY[ib + wir*32 + ni*16 + lc];

    f32x4 dacc[2][4];
    #pragma unroll
    for (int a = 0; a < 2; ++a)
        #pragma unroll
        for (int b = 0; b < 4; ++b)
            dacc[a][b] = (f32x4){0.f, 0.f, 0.f, 0.f};
    float rs[2] = {0.f, 0.f};

    // zero this block's first K-tile; drained by the prologue VMCNT(8)
    zero_tile(Kout, ib, jbase, t);

    for (int jt = 0; jt < NJT; ++jt) {
        const int jb = jbase + jt * BN;

        // zero NEXT tile (issued before staging: drained by counted vmcnt
        // a full iteration before that tile's sparse stores)
        if (jt + 1 < NJT)
            zero_tile(Kout, ib, jb + BN, t);

        // ---- prologue: stage s0->b0, s1->b1, s2->b2, then XT2 ----
        {
            const u16 *Ap, *Bp; int kc;
            get_ops(Ah, Al, Bh, Bl, 0, &Ap, &Bp, &kc);
            stage_ab8(Ap, Bp, ib, jb, kc, smem, wid, lane);
            get_ops(Ah, Al, Bh, Bl, 1, &Ap, &Bp, &kc);
            stage_ab8(Ap, Bp, ib, jb, kc, smem + 16384, wid, lane);
            get_ops(Ah, Al, Bh, Bl, 2, &Ap, &Bp, &kc);
            stage_ab8(Ap, Bp, ib, jb, kc, smem + 32768, wid, lane);
        }
        #pragma unroll
        for (int c = 0; c < 4; ++c) {
            int chunk = wid * 4 + c;              // 0..31
            int dd = chunk * 4 + lq;              // 0..127
            int ch = lc ^ (dd & 7);               // pre-swizzled 16B granule
            GLDS16(XST + (size_t)dd * NN + jb + ch*8,
                   smem + 65536 + (size_t)chunk * 1024);
        }
        VMCNT(8);           // keep 8 youngest (s1,s2,XT2); zeros + prior
                            // sparse stores + s0 drained
        BARRIER();

        f32x4 acc[4][2];    // [mj][ni]
        #pragma unroll
        for (int a = 0; a < 4; ++a)
            #pragma unroll
            for (int b = 0; b < 2; ++b)
                acc[a][b] = (f32x4){0.f, 0.f, 0.f, 0.f};

        // ---- main pipeline: 12 regions, 4 buffers, stage 3 ahead ----
        #pragma unroll 4
        for (int kg = 0; kg < NREG; ++kg) {
            if (kg <= NREG - 4) {                 // kg <= 8: stage s_{kg+3}
                const u16 *Ap, *Bp; int kc;
                get_ops(Ah, Al, Bh, Bl, kg + 3, &Ap, &Bp, &kc);
                stage_ab8(Ap, Bp, ib, jb, kc, smem + ((kg + 3) & 3) * 16384, wid, lane);
            }
            const u16* BufA = (const u16*)(smem + (kg & 3) * 16384);  // YS rows
            const u16* BufB = BufA + 4096;                             // X rows

            bf16x8 xf[4], yf[2];
            #pragma unroll
            for (int mj = 0; mj < 4; ++mj) {
                const int br = wjc*64 + mj*16 + lc;
                xf[mj] = *reinterpret_cast<const bf16x8*>(
                    BufB + br * BK + SWZ_CHUNK(br, lq) * 8);
            }
            #pragma unroll
            for (int ni = 0; ni < 2; ++ni) {
                const int ar = wir*32 + ni*16 + lc;
                yf[ni] = *reinterpret_cast<const bf16x8*>(
                    BufA + ar * BK + SWZ_CHUNK(ar, lq) * 8);
            }
            __builtin_amdgcn_s_setprio(1);
            #pragma unroll
            for (int mj = 0; mj < 4; ++mj)
                #pragma unroll
                for (int ni = 0; ni < 2; ++ni)
                    acc[mj][ni] = __builtin_amdgcn_mfma_f32_16x16x32_bf16(
                        xf[mj], yf[ni], acc[mj][ni], 0, 0, 0);
            __builtin_amdgcn_s_setprio(0);

            // "keep N youngest" ledger; next region needs s_{kg+1} complete
            if (kg <= 1)             VMCNT(8);  // keep {s_{kg+2},s_{kg+3},XT2}
            else if (kg <= NREG - 4) VMCNT(4);  // keep {s_{kg+2},s_{kg+3}}
            else if (kg == NREG - 3) VMCNT(2);  // keep {s11}
            else if (kg == NREG - 2) VMCNT(0);  // all staging done
            if (kg < NREG - 1) BARRIER();
            // last region: no barrier — epilogue touches no LDS; the
            // __syncthreads_count below fences before A2 overwrites b0/b1
            // (last readers: regions 8 (b0) and 9 (b1), behind barriers).
        }

        // ---- epilogue: K = exp(acc - 0.5qY - 0.5qX); SPARSE float4 Kout
        //      (tile pre-zeroed); kq kept in acc for phase 2 ----
        float tmax = 0.f;
        #pragma unroll
        for (int mj = 0; mj < 4; ++mj) {
            const int jl = wjc*64 + mj*16 + lq*4;      // local j of reg 0
            float4 qXv = *reinterpret_cast<const float4*>(qX + jb + jl);
            qXv.x *= 0.5f; qXv.y *= 0.5f; qXv.z *= 0.5f; qXv.w *= 0.5f;
            #pragma unroll
            for (int ni = 0; ni < 2; ++ni) {
                const int il = wir*32 + ni*16 + lc;    // local i
                float kq0 = __expf(acc[mj][ni][0] - qYh[ni] - qXv.x);
                float kq1 = __expf(acc[mj][ni][1] - qYh[ni] - qXv.y);
                float kq2 = __expf(acc[mj][ni][2] - qYh[ni] - qXv.z);
                float kq3 = __expf(acc[mj][ni][3] - qYh[ni] - qXv.w);
                rs[ni] += kq0 + kq1 + kq2 + kq3;
                float m4 = fmaxf(fmaxf(kq0, kq1), fmaxf(kq2, kq3));
                tmax = fmaxf(tmax, m4);
                if (m4 > THRESH)
                    *reinterpret_cast<float4*>(
                        Kout + (size_t)(ib + il) * NN + jb + jl) =
                        make_float4(kq0, kq1, kq2, kq3);
                acc[mj][ni][0] = kq0; acc[mj][ni][1] = kq1;
                acc[mj][ni][2] = kq2; acc[mj][ni][3] = kq3;
            }
        }

        // tile-wide nonzero test (full barrier, block-uniform result)
        const int nz = __syncthreads_count(tmax > THRESH);
        if (nz != 0) {
            // bf16 K into A2 [i][j] row-major, 16B-granule XOR swizzle
            #pragma unroll
            for (int mj = 0; mj < 4; ++mj) {
                const int jl = wjc*64 + mj*16 + lq*4;
                #pragma unroll
                for (int ni = 0; ni < 2; ++ni) {
                    const int il = wir*32 + ni*16 + lc;
                    u32 p0 = (u32)f2bf(acc[mj][ni][0]) | ((u32)f2bf(acc[mj][ni][1]) << 16);
                    u32 p1 = (u32)f2bf(acc[mj][ni][2]) | ((u32)f2bf(acc[mj][ni][3]) << 16);
                    const int by = il*256 + ((jl*2) ^ ((il & 7) << 4));
                    *reinterpret_cast<uint2*>(smem + by) = make_uint2(p0, p1);
                }
            }
            __syncthreads();   // A2 visible to all

            // ---- phase 2: dacc[i][d] += K_tile[i][j] * XS[j][d] ----
            #pragma unroll
            for (int kb = 0; kb < 4; ++kb) {
                bf16x8 pa[2], pb[4];
                #pragma unroll
                for (int mi = 0; mi < 2; ++mi) {
                    const int il = wir*32 + mi*16 + lc;
                    const int gr = (kb*4 + lq) ^ (il & 7);
                    pa[mi] = *reinterpret_cast<const bf16x8*>(smem + il*256 + gr*16);
                }
                #pragma unroll
                for (int di = 0; di < 4; ++di) {
                    const int dl = wjc*64 + di*16 + lc;
                    const int gr = (kb*4 + lq) ^ (dl & 7);
                    pb[di] = *reinterpret_cast<const bf16x8*>(smem + 65536 + dl*256 + gr*16);
                }
                #pragma unroll
                for (int mi = 0; mi < 2; ++mi)
                    #pragma unroll
                    for (int di = 0; di < 4; ++di)
                        dacc[mi][di] = __builtin_amdgcn_mfma_f32_16x16x32_bf16(
                            pa[mi], pb[di], dacc[mi][di], 0, 0, 0);
            }
            __syncthreads();   // phase-2 reads done before next jt restages
        }
        // nz==0: tile contributes nothing; __syncthreads_count already fenced
        // the epilogue, and A2 was never written, so restaging is safe.
    }

    // ---- write out dacc: plain stores to per-jsp partial, or atomic ----
    if (usePart) {
        float* P = daccOut + (size_t)jsp * NN * DD;
        #pragma unroll
        for (int mi = 0; mi < 2; ++mi) {
            #pragma unroll
            for (int di = 0; di < 4; ++di) {
                const int col = wjc*64 + di*16 + lc;
                #pragma unroll
                for (int rr = 0; rr < 4; ++rr) {
                    const int row = ib + wir*32 + mi*16 + lq*4 + rr;
                    P[(size_t)row * DD + col] = dacc[mi][di][rr];
                }
            }
        }
    } else {
        #pragma unroll
        for (int mi = 0; mi < 2; ++mi) {
            #pragma unroll
            for (int di = 0; di < 4; ++di) {
                const int col = wjc*64 + di*16 + lc;
                #pragma unroll
                for (int rr = 0; rr < 4; ++rr) {
                    const int row = ib + wir*32 + mi*16 + lq*4 + rr;
                    atomicAdd(&daccOut[(size_t)row * DD + col], dacc[mi][di][rr]);
                }
            }
        }
    }
    #pragma unroll
    for (int ni = 0; ni < 2; ++ni) {
        float v = rs[ni];
        v += __shfl_xor(v, 16);
        v += __shfl_xor(v, 32);
        if (lq == 0)
            atomicAdd(&rowsum[ib + wir*32 + ni*16 + lc], v);
    }
}

// dK = 2*(rowsum[i]*YS[i][d] - acc[i][d]); acc = sum of partials (usePart)
// or lives in the dK buffer itself (atomic fallback, in-place).
__global__ __launch_bounds__(256) void k3_finalize(
    const float* __restrict__ rowsum, const float* __restrict__ YSrm,
    float* __restrict__ dK, const float* __restrict__ parts, int usePart)
{
    int idx = blockIdx.x * 256 + threadIdx.x;
    int i = idx >> 7;
    float a;
    if (usePart) {
        a = 0.f;
        #pragma unroll
        for (int s = 0; s < JSPLIT; ++s)
            a += parts[(size_t)s * NN * DD + idx];
    } else {
        a = dK[idx];
    }
    dK[idx] = 2.0f * (rowsum[i] * YSrm[idx] - a);
}

extern "C" void kernel_launch(void* const* d_in, const int* in_sizes, int n_in,
                              void* d_out, int out_size, void* d_ws, size_t ws_size,
                              hipStream_t stream)
{
    const float* X = (const float*)d_in[0];
    const float* Y = (const float*)d_in[1];
    const float* S = (const float*)d_in[2];
    float* Kout = (float*)d_out;
    float* dK   = Kout + (size_t)NN * NN;

    u16* Ah  = (u16*)d_ws;
    u16* Al  = Ah + (size_t)NN * KP;
    u16* Bh  = Al + (size_t)NN * KP;
    u16* Bl  = Bh + (size_t)NN * KP;
    u16* XST = Bl + (size_t)NN * KP;
    float* YSrm = (float*)(XST + (size_t)DD * NN);
    float* qX   = YSrm + (size_t)NN * DD;
    float* qY   = qX + NN;
    float* rsum = qY + NN;
    float* parts = rsum + NN;

    const size_t baseBytes = (size_t)((char*)(parts) - (char*)d_ws);
    const size_t needBytes = baseBytes + (size_t)JSPLIT * NN * DD * sizeof(float);
    const int usePart = (ws_size >= needBytes) ? 1 : 0;

    hipMemsetAsync(rsum, 0, (size_t)NN * sizeof(float), stream);
    if (!usePart)
        hipMemsetAsync(dK, 0, (size_t)NN * DD * sizeof(float), stream);

    float* daccOut = usePart ? parts : dK;

    k1_precompute<<<NN / 16, 256, 0, stream>>>(X, Y, S, Ah, Al, Bh, Bl, XST, YSrm, qX, qY);
    k2_main<<<64 * JSPLIT, 512, 0, stream>>>(Ah, Al, Bh, Bl, XST, qX, qY,
                                             Kout, daccOut, rsum, usePart);
    k3_finalize<<<(NN * DD) / 256, 256, 0, stream>>>(rsum, YSrm, dK, parts, usePart);
}

// Round 17
// 170.958 us; speedup vs baseline: 1.7862x; 1.1894x over previous
//
#include <hip/hip_runtime.h>
#include <cstddef>
#include <cstdint>

#define NN 8192
#define DD 128
#define KP 128          // panel K-dim: cross = 2 * YS @ X^T  (S symmetric)
#define BM 128
#define BN 128
#define BK 32
#define NREG 12         // 3 passes (Ah.Bh, Ah.Bl, Al.Bh) x 4 k-steps
#define JSPLIT 4
#define JRANGE (NN / JSPLIT)    // 2048
#define NJT (JRANGE / BN)       // 16
#define THRESH 1e-32f   // K below this is stored as 0 / tile-skipped

typedef __attribute__((ext_vector_type(8))) short bf16x8;
typedef __attribute__((ext_vector_type(4))) float f32x4;
typedef unsigned short u16;
typedef unsigned int   u32;

__device__ __forceinline__ u16 f2bf(float x) {
    u32 u = __float_as_uint(x);
    u32 r = (u + 0x7fffu + ((u >> 16) & 1u)) >> 16;   // round-to-nearest-even
    return (u16)r;
}
__device__ __forceinline__ float bf2f(u16 h) {
    return __uint_as_float(((u32)h) << 16);
}

// async global->LDS, 16B per lane; LDS dest is wave-uniform base (+lane*16 by HW)
#define GLDS16(gp, lp) __builtin_amdgcn_global_load_lds( \
    (const __attribute__((address_space(1))) void*)(gp), \
    (__attribute__((address_space(3))) void*)(lp), 16, 0, 0)

#define VMCNT(n) asm volatile("s_waitcnt vmcnt(" #n ")" ::: "memory")
#define BARRIER() do { __builtin_amdgcn_s_barrier(); asm volatile("" ::: "memory"); } while (0)

// 16B-chunk swizzle within a 64B staging row: free 2-way bank pattern on read
#define SWZ_CHUNK(row, c) ((c) ^ (((row) >> 1) & 3))

// ---------------------------------------------------------------------------
// k1: XS=X@S, YS=Y@S, qX, qY; bf16 hi/lo panels Ah/Al=YS, Bh/Bl=X
// (row-major [8192][128]), XST = bf16 XS^T [128][8192], YSrm fp32 [8192][128].
// ---------------------------------------------------------------------------
__global__ __launch_bounds__(256) void k1_precompute(
    const float* __restrict__ X, const float* __restrict__ Y,
    const float* __restrict__ S,
    u16* __restrict__ Ah, u16* __restrict__ Al,
    u16* __restrict__ Bh, u16* __restrict__ Bl,
    u16* __restrict__ XST, float* __restrict__ YSrm,
    float* __restrict__ qX, float* __restrict__ qY)
{
    __shared__ float Xs[16][128];
    __shared__ float Ys[16][128];
    __shared__ float XSb[16][129];
    __shared__ float YSb[16][129];
    const int t  = threadIdx.x;
    const int i0 = blockIdx.x * 16;

    #pragma unroll
    for (int p = 0; p < 2; ++p) {
        int f4 = t + p * 256;          // 0..511
        int r  = f4 >> 5;
        int c  = (f4 & 31) * 4;
        *reinterpret_cast<float4*>(&Xs[r][c]) =
            *reinterpret_cast<const float4*>(X + (size_t)(i0 + r) * DD + c);
        *reinterpret_cast<float4*>(&Ys[r][c]) =
            *reinterpret_cast<const float4*>(Y + (size_t)(i0 + r) * DD + c);
    }
    __syncthreads();

    const int d    = t & 127;
    const int half = t >> 7;
    float xsa[8], ysa[8];
    #pragma unroll
    for (int r = 0; r < 8; ++r) { xsa[r] = 0.f; ysa[r] = 0.f; }
    for (int k = 0; k < DD; ++k) {
        float sv = S[k * DD + d];
        #pragma unroll
        for (int r = 0; r < 8; ++r) {
            xsa[r] = fmaf(Xs[half*8 + r][k], sv, xsa[r]);
            ysa[r] = fmaf(Ys[half*8 + r][k], sv, ysa[r]);
        }
    }
    #pragma unroll
    for (int r = 0; r < 8; ++r) {
        XSb[half*8 + r][d] = xsa[r];
        YSb[half*8 + r][d] = ysa[r];
    }
    __syncthreads();

    if (t < 16) {
        float s = 0.f;
        for (int k = 0; k < DD; ++k) s += Xs[t][k] * XSb[t][k];
        qX[i0 + t] = s;
    } else if (t < 32) {
        int r = t - 16;
        float s = 0.f;
        for (int k = 0; k < DD; ++k) s += Ys[r][k] * YSb[r][k];
        qY[i0 + r] = s;
    }

    // hi/lo split panels (YS -> A, X -> B), 2 cols per u32 store
    #pragma unroll
    for (int p = 0; p < 4; ++p) {
        int e  = t + p * 256;          // 0..1023
        int r  = e >> 6;               // 0..15
        int c2 = (e & 63) * 2;         // 0,2,..,126
        float a0 = YSb[r][c2], a1 = YSb[r][c2 + 1];
        float b0 = Xs[r][c2],  b1 = Xs[r][c2 + 1];
        u16 ah0 = f2bf(a0), ah1 = f2bf(a1);
        u16 al0 = f2bf(a0 - bf2f(ah0)), al1 = f2bf(a1 - bf2f(ah1));
        u16 bh0 = f2bf(b0), bh1 = f2bf(b1);
        u16 bl0 = f2bf(b0 - bf2f(bh0)), bl1 = f2bf(b1 - bf2f(bh1));
        size_t off = (size_t)(i0 + r) * KP + c2;
        *reinterpret_cast<u32*>(Ah + off) = (u32)ah0 | ((u32)ah1 << 16);
        *reinterpret_cast<u32*>(Al + off) = (u32)al0 | ((u32)al1 << 16);
        *reinterpret_cast<u32*>(Bh + off) = (u32)bh0 | ((u32)bh1 << 16);
        *reinterpret_cast<u32*>(Bl + off) = (u32)bl0 | ((u32)bl1 << 16);
    }
    // XS^T bf16
    #pragma unroll
    for (int p = 0; p < 8; ++p) {
        int e  = t + p * 256;          // 0..2047
        int dd = e >> 4;               // 0..127
        int r  = e & 15;
        XST[(size_t)dd * NN + i0 + r] = f2bf(XSb[r][dd]);
    }
    // YS fp32 row-major
    #pragma unroll
    for (int p = 0; p < 8; ++p) {
        int e  = t + p * 256;
        int r  = e >> 7;
        int dd = e & 127;
        YSrm[(size_t)(i0 + r) * DD + dd] = YSb[r][dd];
    }
}

// ---------------------------------------------------------------------------
// k2 (1024 threads = 16 waves, 96 KB LDS -> 1 block/CU):
// Both constraints at once: 16 waves/CU (4/SIMD, R8's proven compute TLP
// ~45us) AND one open 64KB output tile per CU (R9/R16-proven: no L2
// write-window overflow -> no HBM RMW amplification, unlike 2 blocks/CU
// in R14/R15). Wave grid 4x4 (i-32 x j-32); 4 MFMA/region/wave.
// acc = YSh.Xh^T + YSh.Xl^T + YSl.Xh^T (K=128, 12 regions); quad = 2*acc.
// 4 staging buffers, 3-ahead prefetch; zeros issued AFTER prologue staging
// so they get ~3 regions of slack before the first wait that covers them.
// Per-wave vmcnt ledger (N = insts issued after the needed one):
//   prologue need s0: s1,s2,XT2(2),zeros(4) -> VMCNT(8)
//   reg 0 need s1: s2,XT2(2),zeros(4),s3 -> (8); reg 1 need s2 -> (8)
//   reg 2 need s3: s4,s5 -> (2) [zeros+XT2 drained, 3 regions late]
//   regs 3-8 -> (2); reg 9 -> (1); reg 10 -> (0); reg 11: none.
// LDS: b0..b3 [0,64K), XT2 [64K,96K); A2 (bf16 K tile) aliases b0+b1.
// ---------------------------------------------------------------------------
__device__ __forceinline__ void get_ops(
    const u16* Ah, const u16* Al, const u16* Bh, const u16* Bl,
    int kg, const u16** Ap, const u16** Bp, int* kc)
{
    const int pass = kg >> 2;
    *kc = (kg & 3) * BK;
    *Ap = (pass == 2) ? Al : Ah;
    *Bp = (pass == 1) ? Bl : Bh;
}

// 16-wave staging: waves 0-7 stage A chunk wid (16 rows), waves 8-15 stage
// B chunk wid-8. One GLDS16 per wave.
__device__ __forceinline__ void stage_ab16(
    const u16* __restrict__ Ap, const u16* __restrict__ Bp,
    int ib, int jb, int kc, unsigned char* lds, int wid, int lane)
{
    const int half = wid >> 3;                     // 0 = A(YS), 1 = B(X)
    const int ch   = wid & 7;                      // chunk in half
    const int rr   = ch * 16 + (lane >> 2);        // row 0..127
    const int cc   = SWZ_CHUNK(rr, lane & 3) * 8;  // swizzled u16 col
    const u16* src = half ? (Bp + (size_t)(jb + rr) * KP + kc + cc)
                          : (Ap + (size_t)(ib + rr) * KP + kc + cc);
    GLDS16(src, lds + half * 8192 + ch * 1024);
}

// zero one 128x128 K-tile (64 KB): 4 float4 stores/thread (1024 threads),
// full 512B rows (complete L2 lines).
__device__ __forceinline__ void zero_tile(
    float* __restrict__ Kout, int ib, int jb, int t)
{
    #pragma unroll
    for (int s = 0; s < 4; ++s) {
        const int idx = s * 1024 + t;         // 0..4095 float4s
        const int row = idx >> 5;             // 0..127 (32 float4 per row)
        const int col = (idx & 31) * 4;
        *reinterpret_cast<float4*>(Kout + (size_t)(ib + row) * NN + jb + col) =
            make_float4(0.f, 0.f, 0.f, 0.f);
    }
}

__global__ __launch_bounds__(1024, 4) void k2_main(
    const u16* __restrict__ Ah, const u16* __restrict__ Al,
    const u16* __restrict__ Bh, const u16* __restrict__ Bl,
    const u16* __restrict__ XST,
    const float* __restrict__ qX, const float* __restrict__ qY,
    float* __restrict__ Kout, float* __restrict__ daccOut,
    float* __restrict__ rowsum, int usePart)
{
    __shared__ unsigned char smem[98304];   // b0..b3 (64K) + XT2 (32K)

    const int t    = threadIdx.x;
    const int wid  = t >> 6;                // 0..15
    const int lane = t & 63;
    const int lq   = lane >> 4;             // quarter 0..3
    const int lc   = lane & 15;
    const int wir  = wid >> 2;              // i 32-block (0..3)
    const int wjc  = wid & 3;               // j 32-block (0..3)

    // per-XCD rectangle: 256 blocks, XCD x owns strips [(x&3)*16,+16)
    // x jsp [(x>>2)*2,+2)  (hot set ~4 MB ~ L2)
    const int bid   = blockIdx.x;
    const int xcd   = bid & 7;
    const int rb    = bid >> 3;             // 0..31
    const int strip = (xcd & 3) * 16 + (rb & 15);
    const int jsp   = (xcd >> 2) * 2 + (rb >> 4);
    const int ib    = strip * BM;
    const int jbase = jsp * JRANGE;

    // per-lane row constants: i = ib + wir*32 + ni*16 + lc  (0.5*qY folded)
    float qYh[2];
    #pragma unroll
    for (int ni = 0; ni < 2; ++ni)
        qYh[ni] = 0.5f * qY[ib + wir*32 + ni*16 + lc];

    f32x4 dacc[2][2];
    #pragma unroll
    for (int a = 0; a < 2; ++a)
        #pragma unroll
        for (int b = 0; b < 2; ++b)
            dacc[a][b] = (f32x4){0.f, 0.f, 0.f, 0.f};
    float rs[2] = {0.f, 0.f};

    // zero this block's first K-tile (drained at first prologue VMCNT(8))
    zero_tile(Kout, ib, jbase, t);

    for (int jt = 0; jt < NJT; ++jt) {
        const int jb = jbase + jt * BN;

        // ---- prologue: stage s0->b0, s1->b1, s2->b2, XT2, THEN zero next
        //      tile (zeros youngest -> not drained by the s0 wait) ----
        {
            const u16 *Ap, *Bp; int kc;
            get_ops(Ah, Al, Bh, Bl, 0, &Ap, &Bp, &kc);
            stage_ab16(Ap, Bp, ib, jb, kc, smem, wid, lane);
            get_ops(Ah, Al, Bh, Bl, 1, &Ap, &Bp, &kc);
            stage_ab16(Ap, Bp, ib, jb, kc, smem + 16384, wid, lane);
            get_ops(Ah, Al, Bh, Bl, 2, &Ap, &Bp, &kc);
            stage_ab16(Ap, Bp, ib, jb, kc, smem + 32768, wid, lane);
        }
        #pragma unroll
        for (int c = 0; c < 2; ++c) {
            int chunk = wid * 2 + c;              // 0..31
            int dd = chunk * 4 + lq;              // 0..127
            int ch = lc ^ (dd & 7);               // pre-swizzled 16B granule
            GLDS16(XST + (size_t)dd * NN + jb + ch*8,
                   smem + 65536 + (size_t)chunk * 1024);
        }
        if (jt + 1 < NJT)
            zero_tile(Kout, ib, jb + BN, t);

        VMCNT(8);           // need s0; after it: s1,s2,XT2(2),zeros(4)
        BARRIER();

        f32x4 acc[2][2];    // [mj][ni]
        #pragma unroll
        for (int a = 0; a < 2; ++a)
            #pragma unroll
            for (int b = 0; b < 2; ++b)
                acc[a][b] = (f32x4){0.f, 0.f, 0.f, 0.f};

        // ---- main pipeline: 12 regions, 4 buffers, stage 3 ahead ----
        #pragma unroll 4
        for (int kg = 0; kg < NREG; ++kg) {
            if (kg <= NREG - 4) {                 // kg <= 8: stage s_{kg+3}
                const u16 *Ap, *Bp; int kc;
                get_ops(Ah, Al, Bh, Bl, kg + 3, &Ap, &Bp, &kc);
                stage_ab16(Ap, Bp, ib, jb, kc, smem + ((kg + 3) & 3) * 16384, wid, lane);
            }
            const u16* BufA = (const u16*)(smem + (kg & 3) * 16384);  // YS rows
            const u16* BufB = BufA + 4096;                             // X rows

            bf16x8 xf[2], yf[2];
            #pragma unroll
            for (int mj = 0; mj < 2; ++mj) {
                const int br = wjc*32 + mj*16 + lc;
                xf[mj] = *reinterpret_cast<const bf16x8*>(
                    BufB + br * BK + SWZ_CHUNK(br, lq) * 8);
            }
            #pragma unroll
            for (int ni = 0; ni < 2; ++ni) {
                const int ar = wir*32 + ni*16 + lc;
                yf[ni] = *reinterpret_cast<const bf16x8*>(
                    BufA + ar * BK + SWZ_CHUNK(ar, lq) * 8);
            }
            __builtin_amdgcn_s_setprio(1);
            #pragma unroll
            for (int mj = 0; mj < 2; ++mj)
                #pragma unroll
                for (int ni = 0; ni < 2; ++ni)
                    acc[mj][ni] = __builtin_amdgcn_mfma_f32_16x16x32_bf16(
                        xf[mj], yf[ni], acc[mj][ni], 0, 0, 0);
            __builtin_amdgcn_s_setprio(0);

            // ledger: N = staging insts issued after the one needed next
            if (kg <= 1)             VMCNT(8);  // need s_{kg+1}
            else if (kg <= NREG - 4) VMCNT(2);  // need s_{kg+1}; keep 2 newest
            else if (kg == NREG - 3) VMCNT(1);  // need s10; keep s11
            else if (kg == NREG - 2) VMCNT(0);  // need s11
            if (kg < NREG - 1) BARRIER();
            // last region: no barrier — epilogue touches no LDS; the
            // __syncthreads_count below fences before A2 overwrites b0/b1
            // (last readers: regions 8 (b0) and 9 (b1), behind barriers).
        }

        // ---- epilogue: K = exp(acc - 0.5qY - 0.5qX); SPARSE float4 Kout
        //      (tile pre-zeroed); kq kept in acc for phase 2 ----
        float tmax = 0.f;
        #pragma unroll
        for (int mj = 0; mj < 2; ++mj) {
            const int jl = wjc*32 + mj*16 + lq*4;      // local j of reg 0
            float4 qXv = *reinterpret_cast<const float4*>(qX + jb + jl);
            qXv.x *= 0.5f; qXv.y *= 0.5f; qXv.z *= 0.5f; qXv.w *= 0.5f;
            #pragma unroll
            for (int ni = 0; ni < 2; ++ni) {
                const int il = wir*32 + ni*16 + lc;    // local i
                float kq0 = __expf(acc[mj][ni][0] - qYh[ni] - qXv.x);
                float kq1 = __expf(acc[mj][ni][1] - qYh[ni] - qXv.y);
                float kq2 = __expf(acc[mj][ni][2] - qYh[ni] - qXv.z);
                float kq3 = __expf(acc[mj][ni][3] - qYh[ni] - qXv.w);
                rs[ni] += kq0 + kq1 + kq2 + kq3;
                float m4 = fmaxf(fmaxf(kq0, kq1), fmaxf(kq2, kq3));
                tmax = fmaxf(tmax, m4);
                if (m4 > THRESH)
                    *reinterpret_cast<float4*>(
                        Kout + (size_t)(ib + il) * NN + jb + jl) =
                        make_float4(kq0, kq1, kq2, kq3);
                acc[mj][ni][0] = kq0; acc[mj][ni][1] = kq1;
                acc[mj][ni][2] = kq2; acc[mj][ni][3] = kq3;
            }
        }

        // tile-wide nonzero test (full barrier, block-uniform result)
        const int nz = __syncthreads_count(tmax > THRESH);
        if (nz != 0) {
            // bf16 K into A2 [i][j] row-major, 16B-granule XOR swizzle
            #pragma unroll
            for (int mj = 0; mj < 2; ++mj) {
                const int jl = wjc*32 + mj*16 + lq*4;
                #pragma unroll
                for (int ni = 0; ni < 2; ++ni) {
                    const int il = wir*32 + ni*16 + lc;
                    u32 p0 = (u32)f2bf(acc[mj][ni][0]) | ((u32)f2bf(acc[mj][ni][1]) << 16);
                    u32 p1 = (u32)f2bf(acc[mj][ni][2]) | ((u32)f2bf(acc[mj][ni][3]) << 16);
                    const int by = il*256 + ((jl*2) ^ ((il & 7) << 4));
                    *reinterpret_cast<uint2*>(smem + by) = make_uint2(p0, p1);
                }
            }
            __syncthreads();   // A2 visible to all

            // ---- phase 2: dacc[i][d] += K_tile[i][j] * XS[j][d] ----
            #pragma unroll
            for (int kb = 0; kb < 4; ++kb) {
                bf16x8 pa[2], pb[2];
                #pragma unroll
                for (int mi = 0; mi < 2; ++mi) {
                    const int il = wir*32 + mi*16 + lc;
                    const int gr = (kb*4 + lq) ^ (il & 7);
                    pa[mi] = *reinterpret_cast<const bf16x8*>(smem + il*256 + gr*16);
                }
                #pragma unroll
                for (int di = 0; di < 2; ++di) {
                    const int dl = wjc*32 + di*16 + lc;
                    const int gr = (kb*4 + lq) ^ (dl & 7);
                    pb[di] = *reinterpret_cast<const bf16x8*>(smem + 65536 + dl*256 + gr*16);
                }
                #pragma unroll
                for (int mi = 0; mi < 2; ++mi)
                    #pragma unroll
                    for (int di = 0; di < 2; ++di)
                        dacc[mi][di] = __builtin_amdgcn_mfma_f32_16x16x32_bf16(
                            pa[mi], pb[di], dacc[mi][di], 0, 0, 0);
            }
            __syncthreads();   // phase-2 reads done before next jt restages
        }
        // nz==0: tile contributes nothing; __syncthreads_count already fenced
        // the epilogue, and A2 was never written, so restaging is safe.
    }

    // ---- write out dacc: plain stores to per-jsp partial, or atomic ----
    if (usePart) {
        float* P = daccOut + (size_t)jsp * NN * DD;
        #pragma unroll
        for (int mi = 0; mi < 2; ++mi) {
            #pragma unroll
            for (int di = 0; di < 2; ++di) {
                const int col = wjc*32 + di*16 + lc;
                #pragma unroll
                for (int rr = 0; rr < 4; ++rr) {
                    const int row = ib + wir*32 + mi*16 + lq*4 + rr;
                    P[(size_t)row * DD + col] = dacc[mi][di][rr];
                }
            }
        }
    } else {
        #pragma unroll
        for (int mi = 0; mi < 2; ++mi) {
            #pragma unroll
            for (int di = 0; di < 2; ++di) {
                const int col = wjc*32 + di*16 + lc;
                #pragma unroll
                for (int rr = 0; rr < 4; ++rr) {
                    const int row = ib + wir*32 + mi*16 + lq*4 + rr;
                    atomicAdd(&daccOut[(size_t)row * DD + col], dacc[mi][di][rr]);
                }
            }
        }
    }
    #pragma unroll
    for (int ni = 0; ni < 2; ++ni) {
        float v = rs[ni];
        v += __shfl_xor(v, 16);
        v += __shfl_xor(v, 32);
        if (lq == 0)
            atomicAdd(&rowsum[ib + wir*32 + ni*16 + lc], v);
    }
}

// dK = 2*(rowsum[i]*YS[i][d] - acc[i][d]); acc = sum of partials (usePart)
// or lives in the dK buffer itself (atomic fallback, in-place).
__global__ __launch_bounds__(256) void k3_finalize(
    const float* __restrict__ rowsum, const float* __restrict__ YSrm,
    float* __restrict__ dK, const float* __restrict__ parts, int usePart)
{
    int idx = blockIdx.x * 256 + threadIdx.x;
    int i = idx >> 7;
    float a;
    if (usePart) {
        a = 0.f;
        #pragma unroll
        for (int s = 0; s < JSPLIT; ++s)
            a += parts[(size_t)s * NN * DD + idx];
    } else {
        a = dK[idx];
    }
    dK[idx] = 2.0f * (rowsum[i] * YSrm[idx] - a);
}

extern "C" void kernel_launch(void* const* d_in, const int* in_sizes, int n_in,
                              void* d_out, int out_size, void* d_ws, size_t ws_size,
                              hipStream_t stream)
{
    const float* X = (const float*)d_in[0];
    const float* Y = (const float*)d_in[1];
    const float* S = (const float*)d_in[2];
    float* Kout = (float*)d_out;
    float* dK   = Kout + (size_t)NN * NN;

    u16* Ah  = (u16*)d_ws;
    u16* Al  = Ah + (size_t)NN * KP;
    u16* Bh  = Al + (size_t)NN * KP;
    u16* Bl  = Bh + (size_t)NN * KP;
    u16* XST = Bl + (size_t)NN * KP;
    float* YSrm = (float*)(XST + (size_t)DD * NN);
    float* qX   = YSrm + (size_t)NN * DD;
    float* qY   = qX + NN;
    float* rsum = qY + NN;
    float* parts = rsum + NN;

    const size_t baseBytes = (size_t)((char*)(parts) - (char*)d_ws);
    const size_t needBytes = baseBytes + (size_t)JSPLIT * NN * DD * sizeof(float);
    const int usePart = (ws_size >= needBytes) ? 1 : 0;

    hipMemsetAsync(rsum, 0, (size_t)NN * sizeof(float), stream);
    if (!usePart)
        hipMemsetAsync(dK, 0, (size_t)NN * DD * sizeof(float), stream);

    float* daccOut = usePart ? parts : dK;

    k1_precompute<<<NN / 16, 256, 0, stream>>>(X, Y, S, Ah, Al, Bh, Bl, XST, YSrm, qX, qY);
    k2_main<<<64 * JSPLIT, 1024, 0, stream>>>(Ah, Al, Bh, Bl, XST, qX, qY,
                                              Kout, daccOut, rsum, usePart);
    k3_finalize<<<(NN * DD) / 256, 256, 0, stream>>>(rsum, YSrm, dK, parts, usePart);
}